// Round 6
// baseline (241.455 us; speedup 1.0000x reference)
//
#include <hip/hip_runtime.h>

// Batched symmetric matrix exponential (fp32 32x32), MFMA-native layout, v9.
//
// Invariant trick (verified v4-v8): all iterates are symmetric polynomials of
// the symmetric input, and MFMA's k-contraction is permutation-invariant.
// Every matrix lives in the MFMA C/D register layout (lane holds column
// m = lane&31; reg r holds row rho(r) = (r&3) + 8*(r>>2) + 4*(lane>>5)).
// Feeding those registers back as both A and B operands computes (M*N)[i][n]
// for symmetric commuting M,N. No layout conversion anywhere.
//
// v9 experiment (persistent waves): v4-v8 time is INVARIANT (~82us) under
// -25% work, +33% occupancy, AGPR pinning, and block-size changes. The only
// constant across all versions is 32768 wavefronts (one per matrix);
// 32768 x ~6cyc of per-wave launch/retire overhead = ~82us — exactly the
// floor. So: launch 2048 single-wave blocks, each grid-striding over 16
// matrices, with next-matrix loads issued before current compute (register
// double-buffer; ~900cyc HBM latency hides under ~4000cyc compute). Divides
// per-wave fixed cost by 16; neutral-or-positive under the rival
// critical-path theory (same matrices/SIMD, plus load hiding).
//
// Algorithm: scaling-and-squaring, degree-8 Taylor via Paterson-Stockmeyer:
// exp(At) ~= W + U*At^4,  At = 2^-s A,
//   W = I + At + At^2/2 + At^3/6,
//   U = I/24 + At/120 + At^2/720 + At^3/5040 + At^4/40320
// (4 matmuls: A2, A3, A4, U*A4), then s squarings; s from
// ||A^4||_inf^(1/4) >= ||A||_2 (spectral bound), theta = 1.2.

typedef _Float16 f16x8 __attribute__((ext_vector_type(8)));
typedef __fp16 hf2 __attribute__((ext_vector_type(2)));
typedef float f32x16 __attribute__((ext_vector_type(16)));
typedef unsigned u32x4 __attribute__((ext_vector_type(4)));

struct Op { f16x8 h0, h1, l0, l1; };

__device__ __forceinline__ Op split(f32x16 mv) {
    unsigned uh[8], ul[8];
#pragma unroll
    for (int j = 0; j < 8; ++j) {
        float x0 = mv[2 * j], x1 = mv[2 * j + 1];
        hf2 h = __builtin_amdgcn_cvt_pkrtz(x0, x1);  // rtz hi pair
        unsigned hu = __builtin_bit_cast(unsigned, h);
        unsigned lu;
        // lo = f16(x - f32(h)): one VOP3P mix op per element.
        asm("v_fma_mixlo_f16 %0, %1, -1.0, %2 op_sel:[0,0,0] op_sel_hi:[1,0,0]"
            : "=v"(lu)
            : "v"(hu), "v"(x0));
        asm("v_fma_mixhi_f16 %0, %1, -1.0, %2 op_sel:[1,0,0] op_sel_hi:[1,0,0]"
            : "+v"(lu)
            : "v"(hu), "v"(x1));
        uh[j] = hu;
        ul[j] = lu;
    }
    Op o;
    o.h0 = __builtin_bit_cast(f16x8, (u32x4){uh[0], uh[1], uh[2], uh[3]});
    o.h1 = __builtin_bit_cast(f16x8, (u32x4){uh[4], uh[5], uh[6], uh[7]});
    o.l0 = __builtin_bit_cast(f16x8, (u32x4){ul[0], ul[1], ul[2], ul[3]});
    o.l1 = __builtin_bit_cast(f16x8, (u32x4){ul[4], ul[5], ul[6], ul[7]});
    return o;
}

__device__ __forceinline__ f32x16 mm6(Op a, Op b, f32x16 d) {
    d = __builtin_amdgcn_mfma_f32_32x32x16_f16(a.h0, b.h0, d, 0, 0, 0);
    d = __builtin_amdgcn_mfma_f32_32x32x16_f16(a.h1, b.h1, d, 0, 0, 0);
    d = __builtin_amdgcn_mfma_f32_32x32x16_f16(a.h0, b.l0, d, 0, 0, 0);
    d = __builtin_amdgcn_mfma_f32_32x32x16_f16(a.h1, b.l1, d, 0, 0, 0);
    d = __builtin_amdgcn_mfma_f32_32x32x16_f16(a.l0, b.h0, d, 0, 0, 0);
    d = __builtin_amdgcn_mfma_f32_32x32x16_f16(a.l1, b.h1, d, 0, 0, 0);
    return d;
}

__device__ __forceinline__ f32x16 loadCD(const float* __restrict__ X,
                                         int mat, int m, int hb4) {
    const float* Xb = X + (size_t)mat * 1024 + m * 32 + hb4;
    f32x16 A;
#pragma unroll
    for (int rq = 0; rq < 4; ++rq) {
        float4 q = *(const float4*)(Xb + rq * 8);
        A[4 * rq + 0] = q.x; A[4 * rq + 1] = q.y;
        A[4 * rq + 2] = q.z; A[4 * rq + 3] = q.w;
    }
    return A;
}

__global__ __launch_bounds__(64) void expm32_v9(const float* __restrict__ X,
                                                float* __restrict__ Y, int B) {
    const int t = threadIdx.x;
    const int m = t & 31;
    const int hb4 = (t >> 5) * 4;
    const int md = m - hb4;
    const int nw = gridDim.x;  // one wave per block

    int mat = blockIdx.x;
    if (mat >= B) return;
    f32x16 A = loadCD(X, mat, m, hb4);

    for (; mat < B; ) {
        const int nxt = mat + nw;
        f32x16 An;
        if (nxt < B) An = loadCD(X, nxt, m, hb4);  // prefetch next matrix

        f32x16 z{};  // zero accumulator

        // unscaled powers (entries stay inside fp16-split range:
        // |A|<~6, |A2|<~250, |A3|<~800, |A4|<~8200 < 65504)
        Op oA = split(A);
        f32x16 A2 = mm6(oA, oA, z);
        Op oA2 = split(A2);
        f32x16 A3 = mm6(oA, oA2, z);   // oA dead after this
        f32x16 A4 = mm6(oA2, oA2, z);  // oA2 dead after this

        // spectral-norm estimate: ||A||_2 <= ||A^4||_inf^(1/4)
        float ssum = 0.f;
#pragma unroll
        for (int i = 0; i < 16; ++i) ssum += fabsf(A4[i]);
        ssum += __shfl_xor(ssum, 32);
        float n4 = ssum;
#pragma unroll
        for (int d = 16; d >= 1; d >>= 1) n4 = fmaxf(n4, __shfl_xor(n4, d));

        // s = clamp(ceil(0.25*log2(n4) - log2(theta)), 0, 30), theta = 1.2
        float lg = 0.25f * __log2f(fmaxf(n4, 1e-35f)) - 0.2630344f;
        int s = (int)ceilf(lg);
        s = s < 0 ? 0 : (s > 30 ? 30 : s);

        const float sc1 = __int_as_float((127 - s) << 23);  // exact 2^-s
        const float sc2 = sc1 * sc1, sc3 = sc2 * sc1, sc4 = sc2 * sc2;
        const float k2 = 0.5f * sc2, k3 = (1.f / 6.f) * sc3;
        const float k5 = (1.f / 120.f) * sc1, k6 = (1.f / 720.f) * sc2,
                    k7 = (1.f / 5040.f) * sc3;

        A4 *= sc4;  // (2^-s A)^4 exactly; must be scaled since it is split

        f32x16 U, W;
#pragma unroll
        for (int r = 0; r < 16; ++r) {
            const int kr = (r & 3) + 8 * (r >> 2);  // rho - hb4
            const bool dg = (kr == md);             // diagonal indicator
            W[r] = (dg ? 1.f : 0.f) + sc1 * A[r] + k2 * A2[r] + k3 * A3[r];
            U[r] = (dg ? (1.f / 24.f) : 0.f) + k5 * A[r] + k6 * A2[r] +
                   k7 * A3[r] + (1.f / 40320.f) * A4[r];
        }

        Op oA4 = split(A4);
        Op oU = split(U);
        f32x16 P = mm6(oU, oA4, W);  // exp(2^-s A) ~= U*At^4 + W

        for (int q = 0; q < s; ++q) {
            Op oP = split(P);
            P = mm6(oP, oP, z);
        }

        // store: P symmetric, so lane m's regs are also ROW m -> 4x float4
        float* Yb = Y + (size_t)mat * 1024 + m * 32 + hb4;
#pragma unroll
        for (int rq = 0; rq < 4; ++rq) {
            float4 q;
            q.x = P[4 * rq + 0]; q.y = P[4 * rq + 1];
            q.z = P[4 * rq + 2]; q.w = P[4 * rq + 3];
            *(float4*)(Yb + rq * 8) = q;
        }

        mat = nxt;
        A = An;
    }
}

extern "C" void kernel_launch(void* const* d_in, const int* in_sizes, int n_in,
                              void* d_out, int out_size, void* d_ws, size_t ws_size,
                              hipStream_t stream) {
    const float* x = (const float*)d_in[0];
    float* y = (float*)d_out;
    int B = in_sizes[0] / 1024;
    int blocks = B < 2048 ? B : 2048;  // persistent waves, 16 matrices each
    expm32_v9<<<blocks, 64, 0, stream>>>(x, y, B);
}

// Round 7
// 221.234 us; speedup vs baseline: 1.0914x; 1.0914x over previous
//
#include <hip/hip_runtime.h>

// Batched symmetric matrix exponential (fp32 32x32), MFMA-native layout, v10.
//
// Invariant trick (verified v4-v9): all iterates are symmetric polynomials of
// the symmetric input, and MFMA's k-contraction is permutation-invariant.
// Every matrix lives in the MFMA C/D register layout (lane holds column
// m = lane&31; reg r holds row rho(r) = (r&3) + 8*(r>>2) + 4*(lane>>5)).
// Feeding those registers back as both A and B operands computes (M*N)[i][n]
// for symmetric commuting M,N. No layout conversion anywhere.
//
// v10 experiment (memory-coalescing / TA-transaction-targeted): time was
// invariant 81-88us across v4-v9 under -25% work, +/-occupancy, AGPR pins,
// and persistent waves — the one shared property was the SCATTERED access
// pattern: per-lane float4 at cross-lane stride 128B means every vector-mem
// instruction touches 64 distinct cachelines at 16/64B density (8 instr x 64
// line-requests = 512 TA transactions per matrix; ~65k/CU ~= 27us floor that
// none of the previous levers touched). Fix: load the C/D slot HONESTLY as
// X[rho*32 + m] (not the symmetry-transposed X[m*32 + rho]) — lane-varying
// part becomes the column, so one scalar dword load = 2 dense rows = 4 fully
// covered lines. 16 scalar loads + 16 scalar stores per matrix = 128
// line-requests vs 512. (v4 already had the dense store; v5 wrongly
// "optimized" it into the scattered float4 form.)
//
// Algorithm (unchanged from v8): scaling-and-squaring, degree-8 Taylor via
// Paterson-Stockmeyer: exp(At) ~= W + U*At^4, At = 2^-s A,
//   W = I + At + At^2/2 + At^3/6,
//   U = I/24 + At/120 + At^2/720 + At^3/5040 + At^4/40320
// (4 matmuls: A2, A3, A4, U*A4), then s squarings; s from
// ||A^4||_inf^(1/4) >= ||A||_2 (spectral bound), theta = 1.2.

typedef _Float16 f16x8 __attribute__((ext_vector_type(8)));
typedef __fp16 hf2 __attribute__((ext_vector_type(2)));
typedef float f32x16 __attribute__((ext_vector_type(16)));
typedef unsigned u32x4 __attribute__((ext_vector_type(4)));

struct Op { f16x8 h0, h1, l0, l1; };

__device__ __forceinline__ Op split(f32x16 mv) {
    unsigned uh[8], ul[8];
#pragma unroll
    for (int j = 0; j < 8; ++j) {
        float x0 = mv[2 * j], x1 = mv[2 * j + 1];
        hf2 h = __builtin_amdgcn_cvt_pkrtz(x0, x1);  // rtz hi pair
        unsigned hu = __builtin_bit_cast(unsigned, h);
        unsigned lu;
        // lo = f16(x - f32(h)): one VOP3P mix op per element.
        asm("v_fma_mixlo_f16 %0, %1, -1.0, %2 op_sel:[0,0,0] op_sel_hi:[1,0,0]"
            : "=v"(lu)
            : "v"(hu), "v"(x0));
        asm("v_fma_mixhi_f16 %0, %1, -1.0, %2 op_sel:[1,0,0] op_sel_hi:[1,0,0]"
            : "+v"(lu)
            : "v"(hu), "v"(x1));
        uh[j] = hu;
        ul[j] = lu;
    }
    Op o;
    o.h0 = __builtin_bit_cast(f16x8, (u32x4){uh[0], uh[1], uh[2], uh[3]});
    o.h1 = __builtin_bit_cast(f16x8, (u32x4){uh[4], uh[5], uh[6], uh[7]});
    o.l0 = __builtin_bit_cast(f16x8, (u32x4){ul[0], ul[1], ul[2], ul[3]});
    o.l1 = __builtin_bit_cast(f16x8, (u32x4){ul[4], ul[5], ul[6], ul[7]});
    return o;
}

__device__ __forceinline__ f32x16 mm6(Op a, Op b, f32x16 d) {
    d = __builtin_amdgcn_mfma_f32_32x32x16_f16(a.h0, b.h0, d, 0, 0, 0);
    d = __builtin_amdgcn_mfma_f32_32x32x16_f16(a.h1, b.h1, d, 0, 0, 0);
    d = __builtin_amdgcn_mfma_f32_32x32x16_f16(a.h0, b.l0, d, 0, 0, 0);
    d = __builtin_amdgcn_mfma_f32_32x32x16_f16(a.h1, b.l1, d, 0, 0, 0);
    d = __builtin_amdgcn_mfma_f32_32x32x16_f16(a.l0, b.h0, d, 0, 0, 0);
    d = __builtin_amdgcn_mfma_f32_32x32x16_f16(a.l1, b.h1, d, 0, 0, 0);
    return d;
}

__global__ __launch_bounds__(64) void expm32_v10(const float* __restrict__ X,
                                                 float* __restrict__ Y) {
    const int t = threadIdx.x;
    const int m = t & 31;
    const int hb4 = (t >> 5) * 4;
    const int md = m - hb4;
    const size_t mat = blockIdx.x;

    // COALESCED load, honest C/D layout: A[r] = X[rho(r)][m].
    // Per instruction: lanes 0-31 read 128 contiguous bytes of row rho,
    // lanes 32-63 of row rho+4 -> 4 dense cachelines (vs 64 scattered).
    const float* Xb = X + mat * 1024 + m;
    f32x16 A;
#pragma unroll
    for (int r = 0; r < 16; ++r) {
        const int rho = (r & 3) + 8 * (r >> 2) + hb4;
        A[r] = Xb[rho * 32];
    }

    f32x16 z{};  // zero accumulator

    // unscaled powers (entries stay well inside fp16-split range:
    // |A|<~6, |A2|<~250, |A3|<~800, |A4|<~8200 < 65504)
    Op oA = split(A);
    f32x16 A2 = mm6(oA, oA, z);
    Op oA2 = split(A2);
    f32x16 A3 = mm6(oA, oA2, z);   // oA dead after this
    f32x16 A4 = mm6(oA2, oA2, z);  // oA2 dead after this

    // spectral-norm estimate: ||A||_2 = ||A^4||_2^(1/4) <= ||A^4||_inf^(1/4).
    float ssum = 0.f;
#pragma unroll
    for (int i = 0; i < 16; ++i) ssum += fabsf(A4[i]);
    ssum += __shfl_xor(ssum, 32);
    float n4 = ssum;
#pragma unroll
    for (int d = 16; d >= 1; d >>= 1) n4 = fmaxf(n4, __shfl_xor(n4, d));

    // s = clamp(ceil(0.25*log2(n4) - log2(theta)), 0, 30), theta = 1.2
    float lg = 0.25f * __log2f(fmaxf(n4, 1e-35f)) - 0.2630344f;
    int s = (int)ceilf(lg);
    s = s < 0 ? 0 : (s > 30 ? 30 : s);

    const float sc1 = __int_as_float((127 - s) << 23);  // exact 2^-s
    const float sc2 = sc1 * sc1, sc3 = sc2 * sc1, sc4 = sc2 * sc2;
    const float k2 = 0.5f * sc2, k3 = (1.f / 6.f) * sc3;
    const float k5 = (1.f / 120.f) * sc1, k6 = (1.f / 720.f) * sc2,
                k7 = (1.f / 5040.f) * sc3;

    A4 *= sc4;  // now (2^-s A)^4 exactly; needed scaled since it gets split

    f32x16 U, W;
#pragma unroll
    for (int r = 0; r < 16; ++r) {
        const int kr = (r & 3) + 8 * (r >> 2);  // rho - hb4
        const bool dg = (kr == md);             // diagonal indicator
        W[r] = (dg ? 1.f : 0.f) + sc1 * A[r] + k2 * A2[r] + k3 * A3[r];
        U[r] = (dg ? (1.f / 24.f) : 0.f) + k5 * A[r] + k6 * A2[r] +
               k7 * A3[r] + (1.f / 40320.f) * A4[r];
    }

    Op oA4 = split(A4);
    Op oU = split(U);
    f32x16 P = mm6(oU, oA4, W);  // exp(2^-s A) ~= U*At^4 + W

    for (int q = 0; q < s; ++q) {
        Op oP = split(P);
        P = mm6(oP, oP, z);
    }

    // COALESCED store, honest layout: Y[rho(r)][m] = P[r] (dense across
    // lanes, no symmetry assumption needed). Same pattern as the load.
    float* Yb = Y + mat * 1024 + m;
#pragma unroll
    for (int r = 0; r < 16; ++r) {
        const int rho = (r & 3) + 8 * (r >> 2) + hb4;
        Yb[rho * 32] = P[r];
    }
}

extern "C" void kernel_launch(void* const* d_in, const int* in_sizes, int n_in,
                              void* d_out, int out_size, void* d_ws, size_t ws_size,
                              hipStream_t stream) {
    const float* x = (const float*)d_in[0];
    float* y = (float*)d_out;
    int B = in_sizes[0] / 1024;
    expm32_v10<<<B, 64, 0, stream>>>(x, y);
}